// Round 1
// baseline (138.850 us; speedup 1.0000x reference)
//
#include <hip/hip_runtime.h>
#include <stdint.h>

// ---- types ----
typedef __bf16 bf16x8 __attribute__((ext_vector_type(8)));
typedef unsigned short u16x8 __attribute__((ext_vector_type(8)));
typedef float f32x4 __attribute__((ext_vector_type(4)));

// Problem constants
#define CC 64
#define HH 64
#define WW 64
#define OO 128
#define BB 4
// K-slots per channel: 9 linear + 45 triu products = 54, padded to 64 (2 MFMA k-steps)
#define KSLOT 64

// upper-triangle pair enumeration (i<=j), 45 pairs
__device__ constexpr int PI_[45] = {
  0,0,0,0,0,0,0,0,0,
  1,1,1,1,1,1,1,1,
  2,2,2,2,2,2,2,
  3,3,3,3,3,3,
  4,4,4,4,4,
  5,5,5,5,
  6,6,6,
  7,7,
  8};
__device__ constexpr int PJ_[45] = {
  0,1,2,3,4,5,6,7,8,
  1,2,3,4,5,6,7,8,
  2,3,4,5,6,7,8,
  3,4,5,6,7,8,
  4,5,6,7,8,
  5,6,7,8,
  6,7,8,
  7,8,
  8};

__device__ __forceinline__ unsigned short f2bf(float f) {
  unsigned int u = __float_as_uint(f);
  u = u + 0x7FFFu + ((u >> 16) & 1u);   // RNE
  return (unsigned short)(u >> 16);
}

__device__ __forceinline__ bf16x8 load8(const unsigned short* p) {
  u16x8 v = *(const u16x8*)p;
  return __builtin_bit_cast(bf16x8, v);
}

__device__ __forceinline__ void async_load16(const unsigned short* g, unsigned short* l) {
  __builtin_amdgcn_global_load_lds(
      (const __attribute__((address_space(1))) unsigned int*)g,
      (__attribute__((address_space(3))) unsigned int*)l, 16, 0, 0);
}

// ---- prep: pack wl + triu(wv) into bf16 Wt[c][n][64], chunk-swizzled ----
// logical slot s of (c,n): s<9 -> wl[n][c][s]; 9<=s<54 -> wv[n][c][i][j] (pair s-9); else 0
// stored at flat index c*8192 + n*64 + ((j_chunk ^ (n&7))*8 + e)   (j_chunk=s>>3, e=s&7)
__global__ void prep_kernel(const float* __restrict__ wl, const float* __restrict__ wv,
                            unsigned short* __restrict__ Wt) {
  int t = blockIdx.x * 256 + threadIdx.x;
  if (t >= CC * OO * KSLOT) return;
  int s = t & 63;
  int n = (t >> 6) & 127;
  int c = t >> 13;
  float v = 0.f;
  if (s < 9) {
    v = wl[(n * CC + c) * 9 + s];
  } else if (s < 54) {
    int p = s - 9, i = 0;
    while (p >= 9 - i) { p -= 9 - i; ++i; }
    int j = i + p;
    v = wv[((n * CC + c) * 9 + i) * 9 + j];
  }
  int jc = s >> 3, e = s & 7;
  int pos = ((jc ^ (n & 7)) << 3) | e;
  Wt[c * (OO * KSLOT) + n * KSLOT + pos] = f2bf(v);
}

// ---- patch-slot filler: wave Q handles slots [Q*16, Q*16+16) for its row ----
template <int Q>
__device__ __forceinline__ void fill_slots(const float p[9], unsigned short* dst) {
  unsigned short h[16];
#pragma unroll
  for (int ss = 0; ss < 16; ++ss) {
    const int s = Q * 16 + ss;  // compile-time after unroll
    float v;
    if (s < 9)        v = p[s];
    else if (s < 54)  v = p[PI_[s - 9]] * p[PJ_[s - 9]];
    else              v = 0.f;
    h[ss] = f2bf(v);
  }
  ((uint4*)dst)[0] = *(const uint4*)&h[0];
  ((uint4*)dst)[1] = *(const uint4*)&h[8];
}

// ---- main fused kernel ----
// grid: 256 blocks = (b, y); block 256 thr = 4 waves (2x2: o-half x x-half)
__global__ __launch_bounds__(256) void qconv_kernel(
    const float* __restrict__ img, const unsigned short* __restrict__ Wt,
    const float* __restrict__ bias, float* __restrict__ out) {
  __shared__ float img_t[3][68];                 // rows y-1..y+1, cols -1..64 (pad)
  __shared__ unsigned short Pt[64][72];          // patch tile [x][slot], +8 pad
  __shared__ unsigned short Wtile[OO * KSLOT];   // weight tile, chunk-swizzled, no pad
  __shared__ float bias_s[OO];

  const int t = threadIdx.x;
  const int lane = t & 63;
  const int wq = t >> 6;       // wave id 0..3 (uniform)
  const int quad = lane >> 4;  // 0..3
  const int u = lane & 15;
  const int wo = wq & 1;       // o-half
  const int wx = wq >> 1;      // x-half
  const int b = blockIdx.x >> 6;
  const int y = blockIdx.x & 63;

  if (t < OO) bias_s[t] = bias[t];

  f32x4 acc[4][2];
#pragma unroll
  for (int mt = 0; mt < 4; ++mt)
#pragma unroll
    for (int nt = 0; nt < 2; ++nt) acc[mt][nt] = (f32x4){0.f, 0.f, 0.f, 0.f};

  for (int c = 0; c < CC; ++c) {
    // --- stage image slab (rows y-1..y+1, padded cols) ---
    if (t < 204) {
      int r = t / 68, cl = t - r * 68;
      float v = 0.f;
      int yy = y + r - 1, xx = cl - 1;
      if (cl < 66 && (unsigned)yy < 64u && (unsigned)xx < 64u)
        v = img[((b * CC + c) * HH + yy) * WW + xx];
      img_t[r][cl] = v;
    }
    // --- stage weight tile async (16 KB, 16 x 1KB wave-chunks) ---
    {
      const unsigned short* gsrc = Wt + c * (OO * KSLOT);
#pragma unroll
      for (int ii = 0; ii < 4; ++ii) {
        int inst = wq * 4 + ii;
        async_load16(gsrc + inst * 512 + lane * 8, &Wtile[inst * 512]);
      }
    }
    __syncthreads();

    // --- build patch tile: row x = lane, this wave's 16 slots ---
    {
      float p[9];
#pragma unroll
      for (int jj = 0; jj < 9; ++jj) p[jj] = img_t[jj / 3][lane + (jj % 3)];
      switch (wq) {
        case 0: fill_slots<0>(p, &Pt[lane][0]);  break;
        case 1: fill_slots<1>(p, &Pt[lane][16]); break;
        case 2: fill_slots<2>(p, &Pt[lane][32]); break;
        default: fill_slots<3>(p, &Pt[lane][48]); break;
      }
    }
    __syncthreads();

    // --- MFMA: A = weights (m-side = o), B = patches (n-side = x) ---
#pragma unroll
    for (int ks = 0; ks < 2; ++ks) {
      bf16x8 bfrag[2];
#pragma unroll
      for (int nt = 0; nt < 2; ++nt) {
        int x = wx * 32 + nt * 16 + u;
        bfrag[nt] = load8(&Pt[x][ks * 32 + quad * 8]);
      }
#pragma unroll
      for (int mt = 0; mt < 4; ++mt) {
        int orow = wo * 64 + mt * 16 + u;
        int jc = ks * 4 + quad;
        bf16x8 afrag = load8(&Wtile[orow * KSLOT + ((jc ^ (orow & 7)) << 3)]);
#pragma unroll
        for (int nt = 0; nt < 2; ++nt)
          acc[mt][nt] =
              __builtin_amdgcn_mfma_f32_16x16x32_bf16(afrag, bfrag[nt], acc[mt][nt], 0, 0, 0);
      }
    }
    __syncthreads();  // protect tiles before next c's staging
  }

  // --- epilogue: D row = o (quad*4+r), col = x (lane&15) ---
#pragma unroll
  for (int mt = 0; mt < 4; ++mt)
#pragma unroll
    for (int nt = 0; nt < 2; ++nt)
#pragma unroll
      for (int r = 0; r < 4; ++r) {
        int o = wo * 64 + mt * 16 + quad * 4 + r;
        int x = wx * 32 + nt * 16 + u;
        out[((b * OO + o) * HH + y) * WW + x] = acc[mt][nt][r] + bias_s[o];
      }
}

extern "C" void kernel_launch(void* const* d_in, const int* in_sizes, int n_in,
                              void* d_out, int out_size, void* d_ws, size_t ws_size,
                              hipStream_t stream) {
  const float* image = (const float*)d_in[0];
  const float* wl = (const float*)d_in[1];
  const float* wv = (const float*)d_in[2];
  const float* bias = (const float*)d_in[3];
  float* out = (float*)d_out;
  unsigned short* Wt = (unsigned short*)d_ws;  // 64*128*64 bf16 = 1 MB

  int prep_elems = CC * OO * KSLOT;
  prep_kernel<<<(prep_elems + 255) / 256, 256, 0, stream>>>(wl, wv, Wt);
  qconv_kernel<<<BB * HH, 256, 0, stream>>>(image, Wt, bias, out);
}